// Round 9
// baseline (20681.996 us; speedup 1.0000x reference)
//
#include <hip/hip_runtime.h>
#include <math.h>

#define T_STEPS 512
#define BATCH   64
#define IDIM    512
#define DDIM    1024
#define KH      1024
#define KX      512
#define KT      1536
#define NBLK    256

typedef unsigned short ushort_t;
typedef __attribute__((ext_vector_type(8))) short short8;
typedef __attribute__((ext_vector_type(4))) short short4v;
typedef __attribute__((ext_vector_type(4))) float f32x4;

__device__ __forceinline__ ushort_t f2bf(float f) {
    unsigned int u = __float_as_uint(f);
    u += 0x7fff + ((u >> 16) & 1);          // RNE
    return (ushort_t)(u >> 16);
}
__device__ __forceinline__ float bf2f(ushort_t s) {
    return __uint_as_float(((unsigned int)s) << 16);
}

// ---------------------------------------------------------------------------
// One-time: weights -> Ab[dc 0..63][g 0..2][s 0..1][m 0..15][k 0..1535] bf16
// (double-bf16 split; unchanged, proven r5/r7)
// ---------------------------------------------------------------------------
__global__ __launch_bounds__(256) void k_build_A(const float* __restrict__ U,
                                                 const float* __restrict__ Ux,
                                                 const float* __restrict__ W,
                                                 const float* __restrict__ Wx,
                                                 ushort_t* __restrict__ Ab) {
    int blk = blockIdx.x;            // 0..191 = dc*3+g
    int dc = blk / 3, g = blk % 3;
    int tid = threadIdx.x;
    int m = tid & 15, kb = tid >> 4;
    int col = dc * 16 + m;
    size_t rowbase = ((((size_t)dc * 3 + g) * 2 + 0) * 16 + m) * KT;
    for (int k = kb; k < KT; k += 16) {
        float w;
        if (g == 2) {
            w = (k < KH) ? Ux[(size_t)k * DDIM + col]
                         : Wx[(size_t)(k - KH) * DDIM + col];
        } else {
            int c2 = col + (g == 1 ? DDIM : 0);
            w = (k < KH) ? U[(size_t)k * (2 * DDIM) + c2]
                         : W[(size_t)(k - KH) * (2 * DDIM) + c2];
        }
        ushort_t w1 = f2bf(w);
        ushort_t w2 = f2bf(w - bf2f(w1));
        Ab[rowbase + k] = w1;
        Ab[rowbase + (size_t)16 * KT + k] = w2;   // s=1
    }
}

// ---------------------------------------------------------------------------
// One-time: state_below -> sbB[t][s][b 0..63][i 0..511] bf16 (split pair)
// (unchanged, proven)
// ---------------------------------------------------------------------------
__global__ __launch_bounds__(256) void k_build_sbB(const float* __restrict__ sb,
                                                   ushort_t* __restrict__ sbB) {
    int blk = blockIdx.x;            // 0..2047 = t*4+bt
    int t = blk >> 2, bt = blk & 3;
    int tid = threadIdx.x;
    int r = tid >> 4, c = tid & 15;
    const float* src = sb + ((size_t)t * BATCH + bt * 16 + r) * IDIM;
    ushort_t* d1 = sbB + ((((size_t)t * 2 + 0) * 4 + bt) * 16 + r) * KX;
    ushort_t* d2 = sbB + ((((size_t)t * 2 + 1) * 4 + bt) * 16 + r) * KX;
#pragma unroll
    for (int rep = 0; rep < 8; ++rep) {
        int i = c * 4 + rep * 64;
        float4 v = *(const float4*)(src + i);
        ushort_t a0 = f2bf(v.x), a1 = f2bf(v.y), a2 = f2bf(v.z), a3 = f2bf(v.w);
        short4v p1 = {(short)a0, (short)a1, (short)a2, (short)a3};
        *(short4v*)(d1 + i) = p1;
        ushort_t b0 = f2bf(v.x - bf2f(a0)), b1 = f2bf(v.y - bf2f(a1));
        ushort_t b2 = f2bf(v.z - bf2f(a2)), b3 = f2bf(v.w - bf2f(a3));
        short4v p2 = {(short)b0, (short)b1, (short)b2, (short)b3};
        *(short4v*)(d2 + i) = p2;
    }
}

// ---------------------------------------------------------------------------
// Two-level grid barrier. bar layout (ints): cnt[xcd] at xcd*32 (128-B lines),
// root at 256, gen at 288. Called by tid==0 only.
// ---------------------------------------------------------------------------
__device__ __forceinline__ void gbar2(int* __restrict__ bar, int xcd, int target) {
    int a = __hip_atomic_fetch_add(&bar[xcd * 32], 1, __ATOMIC_ACQ_REL,
                                   __HIP_MEMORY_SCOPE_AGENT);
    if (a == (NBLK / 8) - 1) {                   // last block of this XCD group
        __hip_atomic_store(&bar[xcd * 32], 0, __ATOMIC_RELAXED,
                           __HIP_MEMORY_SCOPE_AGENT);
        int r = __hip_atomic_fetch_add(&bar[256], 1, __ATOMIC_ACQ_REL,
                                       __HIP_MEMORY_SCOPE_AGENT);
        if (r == 7) {
            __hip_atomic_store(&bar[256], 0, __ATOMIC_RELAXED,
                               __HIP_MEMORY_SCOPE_AGENT);
            __hip_atomic_store(&bar[288], target, __ATOMIC_RELEASE,
                               __HIP_MEMORY_SCOPE_AGENT);
        }
    }
    while (__hip_atomic_load(&bar[288], __ATOMIC_ACQUIRE,
                             __HIP_MEMORY_SCOPE_AGENT) < target)
        __builtin_amdgcn_s_sleep(2);
}

// ---------------------------------------------------------------------------
// Persistent scan. Grid 256 = (dc 0..63) x (bq 0..3) XCD-swizzled; 768 thr =
// 12 waves, wave ku = K-slice of 128 (ku<8: h, ku>=8: x). r7's exact compute
// core (direct global reads, no LDS staging, triple-product double-bf16).
// Per step: MFMA -> red LDS -> epilogue (h-old in regs) -> release fence
// (tid 0) -> two-level barrier -> acquire fence (tid 0).
// ---------------------------------------------------------------------------
__global__ __launch_bounds__(768, 1) void k_scan(
    const ushort_t* __restrict__ Ab, const ushort_t* __restrict__ sbB,
    const float* __restrict__ mask, const float* __restrict__ bW,
    const float* __restrict__ bWx, ushort_t* __restrict__ hB,
    float* __restrict__ out, int* __restrict__ bar)
{
    __shared__ float red[12 * 3 * 4 * 64];   // 36,864 B

    int tid  = threadIdx.x;
    int lane = tid & 63;
    int ku   = tid >> 6;                 // 0..11 = K-slice
    int bid  = blockIdx.x;
    int xcd  = bid & 7, j = bid >> 3;    // j 0..31
    int dc   = xcd * 8 + (j & 7);        // 0..63
    int bq   = j >> 3;                   // 0..3

    int m = lane & 15, q = lane >> 4;
    int b_lane = bq * 16 + m;

    bool isH  = (ku < 8);
    int kbase = isH ? ku * 128 : KH + (ku - 8) * 128;

    const ushort_t* a1[3];
    const ushort_t* a2[3];
#pragma unroll
    for (int g = 0; g < 3; ++g) {
        a1[g] = Ab + ((((size_t)dc * 3 + g) * 2 + 0) * 16 + m) * KT + kbase;
        a2[g] = a1[g] + (size_t)16 * KT;
    }

    // ---- epilogue-thread persistent state (one (d,b) per thread, tid<256)
    int ed = 0, eb = 0;
    float hold = 0.f, bR = 0.f, bU = 0.f, bX = 0.f;
    if (tid < 256) {
        int dl = tid >> 4, b16 = tid & 15;
        ed = dc * 16 + dl;
        eb = bq * 16 + b16;
        bR = bW[ed];
        bU = bW[DDIM + ed];
        bX = bWx[ed];
    }

    const size_t hP = (size_t)2 * 64 * KH;   // elems per ping buffer

    for (int t = 0; t < T_STEPS; ++t) {
        const ushort_t* hBin  = hB + (size_t)(t & 1) * hP;
        ushort_t*       hBout = hB + (size_t)((t + 1) & 1) * hP;
        const ushort_t* sbB_t = sbB + (size_t)t * (2 * 64 * KX);

        const ushort_t* b1row;
        size_t sstr;
        if (isH) { b1row = hBin  + (size_t)b_lane * KH + kbase;        sstr = (size_t)64 * KH; }
        else     { b1row = sbB_t + (size_t)b_lane * KX + (kbase - KH); sstr = (size_t)64 * KX; }
        const ushort_t* b2row = b1row + sstr;

        f32x4 accA[3] = {{0,0,0,0},{0,0,0,0},{0,0,0,0}};
        f32x4 accB[3] = {{0,0,0,0},{0,0,0,0},{0,0,0,0}};

        if (!(t == 0 && isH)) {
#pragma unroll
            for (int ks = 0; ks < 4; ks += 2) {
                int ko0 = ks * 32 + q * 8;
                int ko1 = ko0 + 32;
                short8 B10 = *(const short8*)(b1row + ko0);
                short8 B20 = *(const short8*)(b2row + ko0);
                short8 B11 = *(const short8*)(b1row + ko1);
                short8 B21 = *(const short8*)(b2row + ko1);
#pragma unroll
                for (int g = 0; g < 3; ++g) {
                    short8 A10 = *(const short8*)(a1[g] + ko0);
                    short8 A20 = *(const short8*)(a2[g] + ko0);
                    short8 A11 = *(const short8*)(a1[g] + ko1);
                    short8 A21 = *(const short8*)(a2[g] + ko1);
                    accA[g] = __builtin_amdgcn_mfma_f32_16x16x32_bf16(A20, B10, accA[g], 0, 0, 0);
                    accA[g] = __builtin_amdgcn_mfma_f32_16x16x32_bf16(A10, B20, accA[g], 0, 0, 0);
                    accA[g] = __builtin_amdgcn_mfma_f32_16x16x32_bf16(A10, B10, accA[g], 0, 0, 0);
                    accB[g] = __builtin_amdgcn_mfma_f32_16x16x32_bf16(A21, B11, accB[g], 0, 0, 0);
                    accB[g] = __builtin_amdgcn_mfma_f32_16x16x32_bf16(A11, B21, accB[g], 0, 0, 0);
                    accB[g] = __builtin_amdgcn_mfma_f32_16x16x32_bf16(A11, B11, accB[g], 0, 0, 0);
                }
            }
        }

#pragma unroll
        for (int g = 0; g < 3; ++g) {
            f32x4 s = accA[g] + accB[g];
#pragma unroll
            for (int rg = 0; rg < 4; ++rg)
                red[((ku * 3 + g) * 4 + rg) * 64 + lane] = s[rg];
        }
        __syncthreads();

        // ---- epilogue: 256 threads, one (d, b) each; h-old in registers
        if (tid < 256) {
            int dl = tid >> 4, b16 = tid & 15;
            int l_src = ((dl >> 2) << 4) + b16;
            int rg = dl & 3;
            float sR = 0.f, sU = 0.f, sHu = 0.f, sXx = 0.f;
#pragma unroll
            for (int k2 = 0; k2 < 12; ++k2) {
                sR += red[((k2 * 3 + 0) * 4 + rg) * 64 + l_src];
                sU += red[((k2 * 3 + 1) * 4 + rg) * 64 + l_src];
                float v2 = red[((k2 * 3 + 2) * 4 + rg) * 64 + l_src];
                if (k2 < 8) sHu += v2; else sXx += v2;
            }
            float mk = mask[(t << 6) + eb];
            float r  = 1.f / (1.f + __expf(-(sR + bR)));
            float u  = 1.f / (1.f + __expf(-(sU + bU)));
            float hc = tanhf(sHu * r + sXx + bX);
            float hnv = u * hold + (1.f - u) * hc;
            hnv = mk * hnv + (1.f - mk) * hold;
            hold = hnv;

            out[(size_t)t * (BATCH * DDIM) + (size_t)eb * DDIM + ed] = hnv;
            ushort_t h1 = f2bf(hnv);
            ushort_t h2 = f2bf(hnv - bf2f(h1));
            hBout[(size_t)eb * KH + ed] = h1;
            hBout[(size_t)64 * KH + (size_t)eb * KH + ed] = h2;
        }

        // ---- publish h + cross-grid barrier + invalidate
        __syncthreads();                         // all waves' stores issued
        if (t + 1 < T_STEPS) {
            if (tid == 0) {
                __builtin_amdgcn_fence(__ATOMIC_RELEASE, "agent");  // wbl2
                gbar2(bar, xcd, t + 1);
                __builtin_amdgcn_fence(__ATOMIC_ACQUIRE, "agent");  // inv L1/L2
            }
            __syncthreads();
        }
    }
}

// ---------------------------------------------------------------------------
extern "C" void kernel_launch(void* const* d_in, const int* in_sizes, int n_in,
                              void* d_out, int out_size, void* d_ws, size_t ws_size,
                              hipStream_t stream) {
    const float* sb   = (const float*)d_in[0];
    const float* mask = (const float*)d_in[1];
    const float* W    = (const float*)d_in[2];
    const float* bW   = (const float*)d_in[3];
    const float* Wx   = (const float*)d_in[4];
    const float* bWx  = (const float*)d_in[5];
    const float* U    = (const float*)d_in[6];
    const float* Ux   = (const float*)d_in[7];
    float* out = (float*)d_out;

    // ws layout (bf16 elems): Ab 9,437,184 | sbB 33,554,432 | hB 2x131,072 | bar
    ushort_t* Ab  = (ushort_t*)d_ws;
    ushort_t* sbB = Ab + (size_t)2 * 3072 * KT;
    ushort_t* hB  = sbB + (size_t)T_STEPS * 2 * 64 * KX;
    int*      bar = (int*)(hB + (size_t)2 * 2 * 64 * KH);

    (void)hipMemsetAsync(bar, 0, 2048, stream);
    k_build_A<<<dim3(192), 256, 0, stream>>>(U, Ux, W, Wx, Ab);
    k_build_sbB<<<dim3(T_STEPS * 4), 256, 0, stream>>>(sb, sbB);

    const ushort_t* AbC = Ab; const ushort_t* sbBC = sbB;
    void* args[] = {(void*)&AbC, (void*)&sbBC, (void*)&mask, (void*)&bW,
                    (void*)&bWx, (void*)&hB, (void*)&out, (void*)&bar};
    (void)hipLaunchCooperativeKernel((const void*)k_scan, dim3(NBLK), dim3(768),
                                     args, 0, stream);
}

// Round 10
// 5386.953 us; speedup vs baseline: 3.8393x; 3.8393x over previous
//
#include <hip/hip_runtime.h>
#include <math.h>

#define T_STEPS 512
#define BATCH   64
#define IDIM    512
#define DDIM    1024
#define KH      1024
#define KX      512
#define KT      1536

typedef unsigned short ushort_t;
typedef __attribute__((ext_vector_type(8))) short short8;
typedef __attribute__((ext_vector_type(4))) short short4v;
typedef __attribute__((ext_vector_type(4))) float f32x4;

__device__ __forceinline__ ushort_t f2bf(float f) {
    unsigned int u = __float_as_uint(f);
    u += 0x7fff + ((u >> 16) & 1);          // RNE
    return (ushort_t)(u >> 16);
}
__device__ __forceinline__ float bf2f(ushort_t s) {
    return __uint_as_float(((unsigned int)s) << 16);
}

// ---------------------------------------------------------------------------
// One-time: weights -> Ab[dc 0..63][g 0..2][s 0..1][m 0..15][k 0..1535] bf16
// (double-bf16 split; s=1 residual kept for possible revert, unread by k_step)
// ---------------------------------------------------------------------------
__global__ __launch_bounds__(256) void k_build_A(const float* __restrict__ U,
                                                 const float* __restrict__ Ux,
                                                 const float* __restrict__ W,
                                                 const float* __restrict__ Wx,
                                                 ushort_t* __restrict__ Ab) {
    int blk = blockIdx.x;            // 0..191 = dc*3+g
    int dc = blk / 3, g = blk % 3;
    int tid = threadIdx.x;
    int m = tid & 15, kb = tid >> 4;
    int col = dc * 16 + m;
    size_t rowbase = ((((size_t)dc * 3 + g) * 2 + 0) * 16 + m) * KT;
    for (int k = kb; k < KT; k += 16) {
        float w;
        if (g == 2) {
            w = (k < KH) ? Ux[(size_t)k * DDIM + col]
                         : Wx[(size_t)(k - KH) * DDIM + col];
        } else {
            int c2 = col + (g == 1 ? DDIM : 0);
            w = (k < KH) ? U[(size_t)k * (2 * DDIM) + c2]
                         : W[(size_t)(k - KH) * (2 * DDIM) + c2];
        }
        ushort_t w1 = f2bf(w);
        ushort_t w2 = f2bf(w - bf2f(w1));
        Ab[rowbase + k] = w1;
        Ab[rowbase + (size_t)16 * KT + k] = w2;   // s=1 (unused this round)
    }
}

// ---------------------------------------------------------------------------
// One-time: state_below -> sbB[t][s][b 0..63][i 0..511] bf16 (split pair)
// (unchanged, proven)
// ---------------------------------------------------------------------------
__global__ __launch_bounds__(256) void k_build_sbB(const float* __restrict__ sb,
                                                   ushort_t* __restrict__ sbB) {
    int blk = blockIdx.x;            // 0..2047 = t*4+bt
    int t = blk >> 2, bt = blk & 3;
    int tid = threadIdx.x;
    int r = tid >> 4, c = tid & 15;
    const float* src = sb + ((size_t)t * BATCH + bt * 16 + r) * IDIM;
    ushort_t* d1 = sbB + ((((size_t)t * 2 + 0) * 4 + bt) * 16 + r) * KX;
    ushort_t* d2 = sbB + ((((size_t)t * 2 + 1) * 4 + bt) * 16 + r) * KX;
#pragma unroll
    for (int rep = 0; rep < 8; ++rep) {
        int i = c * 4 + rep * 64;
        float4 v = *(const float4*)(src + i);
        ushort_t a0 = f2bf(v.x), a1 = f2bf(v.y), a2 = f2bf(v.z), a3 = f2bf(v.w);
        short4v p1 = {(short)a0, (short)a1, (short)a2, (short)a3};
        *(short4v*)(d1 + i) = p1;
        ushort_t b0 = f2bf(v.x - bf2f(a0)), b1 = f2bf(v.y - bf2f(a1));
        ushort_t b2 = f2bf(v.z - bf2f(a2)), b3 = f2bf(v.w - bf2f(a3));
        short4v p2 = {(short)b0, (short)b1, (short)b2, (short)b3};
        *(short4v*)(d2 + i) = p2;
    }
}

// ---------------------------------------------------------------------------
// Per-step kernel (r7 structure, dual-product). Grid 256 = (dc 0..63) x
// (bq 0..3), XCD-swizzled. 768 threads = 12 waves, wave ku = K-slice of 128
// (ku<8: h-part, ku>=8: x-part). No LDS staging; direct global reads.
// acc += A1*B2 + A1*B1  (= w1·(h1+h2); dropped w2·h1 term ~2e-3 preact err).
// One __syncthreads, then 256 threads reduce + gates + stores.
// ---------------------------------------------------------------------------
__global__ __launch_bounds__(768, 1) void k_step(
    const ushort_t* __restrict__ Ab, const ushort_t* __restrict__ sbB_t,
    const ushort_t* __restrict__ hBin, ushort_t* __restrict__ hBout,
    float* __restrict__ out_t, const float* __restrict__ out_prev,
    const float* __restrict__ bW, const float* __restrict__ bWx,
    const float* __restrict__ mask_t, int first)
{
    __shared__ float red[12 * 3 * 4 * 64];   // 36,864 B

    int tid  = threadIdx.x;
    int lane = tid & 63;
    int ku   = tid >> 6;                 // 0..11 = K-slice
    int bid  = blockIdx.x;
    int xcd  = bid & 7, j = bid >> 3;    // j 0..31
    int dc   = xcd * 8 + (j & 7);        // 0..63
    int bq   = j >> 3;                   // 0..3

    int m = lane & 15, q = lane >> 4;
    int b_lane = bq * 16 + m;

    bool isH  = (ku < 8);
    int kbase = isH ? ku * 128 : KH + (ku - 8) * 128;

    const ushort_t* b1row;
    size_t sstr;
    if (isH) { b1row = hBin  + (size_t)b_lane * KH + kbase;        sstr = (size_t)64 * KH; }
    else     { b1row = sbB_t + (size_t)b_lane * KX + (kbase - KH); sstr = (size_t)64 * KX; }
    const ushort_t* b2row = b1row + sstr;

    const ushort_t* a1[3];
#pragma unroll
    for (int g = 0; g < 3; ++g)
        a1[g] = Ab + ((((size_t)dc * 3 + g) * 2 + 0) * 16 + m) * KT + kbase;

    f32x4 accA[3] = {{0,0,0,0},{0,0,0,0},{0,0,0,0}};
    f32x4 accB[3] = {{0,0,0,0},{0,0,0,0},{0,0,0,0}};

    if (!(first && isH)) {
#pragma unroll
        for (int ks = 0; ks < 4; ks += 2) {
            int ko0 = ks * 32 + q * 8;
            int ko1 = ko0 + 32;
            short8 B10 = *(const short8*)(b1row + ko0);
            short8 B20 = *(const short8*)(b2row + ko0);
            short8 B11 = *(const short8*)(b1row + ko1);
            short8 B21 = *(const short8*)(b2row + ko1);
#pragma unroll
            for (int g = 0; g < 3; ++g) {
                short8 A10 = *(const short8*)(a1[g] + ko0);
                short8 A11 = *(const short8*)(a1[g] + ko1);
                accA[g] = __builtin_amdgcn_mfma_f32_16x16x32_bf16(A10, B20, accA[g], 0, 0, 0);
                accA[g] = __builtin_amdgcn_mfma_f32_16x16x32_bf16(A10, B10, accA[g], 0, 0, 0);
                accB[g] = __builtin_amdgcn_mfma_f32_16x16x32_bf16(A11, B21, accB[g], 0, 0, 0);
                accB[g] = __builtin_amdgcn_mfma_f32_16x16x32_bf16(A11, B11, accB[g], 0, 0, 0);
            }
        }
    }

#pragma unroll
    for (int g = 0; g < 3; ++g) {
        f32x4 s = accA[g] + accB[g];
#pragma unroll
        for (int rg = 0; rg < 4; ++rg)
            red[((ku * 3 + g) * 4 + rg) * 64 + lane] = s[rg];
    }
    __syncthreads();

    // ---- epilogue: 256 threads, one (d, b) each
    if (tid < 256) {
        int dl = tid >> 4, b16 = tid & 15;
        int l_src = ((dl >> 2) << 4) + b16;
        int rg = dl & 3;
        float sR = 0.f, sU = 0.f, sHu = 0.f, sXx = 0.f;
#pragma unroll
        for (int k2 = 0; k2 < 12; ++k2) {
            sR += red[((k2 * 3 + 0) * 4 + rg) * 64 + l_src];
            sU += red[((k2 * 3 + 1) * 4 + rg) * 64 + l_src];
            float v2 = red[((k2 * 3 + 2) * 4 + rg) * 64 + l_src];
            if (k2 < 8) sHu += v2; else sXx += v2;
        }
        int d = dc * 16 + dl;
        int b = bq * 16 + b16;
        float hOld = first ? 0.f : out_prev[(size_t)b * DDIM + d];
        float mk = mask_t[b];
        float r  = 1.f / (1.f + __expf(-(sR + bW[d])));
        float u  = 1.f / (1.f + __expf(-(sU + bW[DDIM + d])));
        float hc = tanhf(sHu * r + sXx + bWx[d]);
        float hnv = u * hOld + (1.f - u) * hc;
        hnv = mk * hnv + (1.f - mk) * hOld;

        out_t[(size_t)b * DDIM + d] = hnv;
        ushort_t h1 = f2bf(hnv);
        ushort_t h2 = f2bf(hnv - bf2f(h1));
        hBout[(size_t)b * KH + d] = h1;
        hBout[(size_t)64 * KH + (size_t)b * KH + d] = h2;
    }
}

// ---------------------------------------------------------------------------
extern "C" void kernel_launch(void* const* d_in, const int* in_sizes, int n_in,
                              void* d_out, int out_size, void* d_ws, size_t ws_size,
                              hipStream_t stream) {
    const float* sb   = (const float*)d_in[0];
    const float* mask = (const float*)d_in[1];
    const float* W    = (const float*)d_in[2];
    const float* bW   = (const float*)d_in[3];
    const float* Wx   = (const float*)d_in[4];
    const float* bWx  = (const float*)d_in[5];
    const float* U    = (const float*)d_in[6];
    const float* Ux   = (const float*)d_in[7];
    float* out = (float*)d_out;

    // ws layout (bf16 elems): Ab 9,437,184 | sbB 33,554,432 | hB 2x131,072
    ushort_t* Ab  = (ushort_t*)d_ws;
    ushort_t* sbB = Ab + (size_t)2 * 3072 * KT;
    ushort_t* hB  = sbB + (size_t)T_STEPS * 2 * 64 * KX;

    k_build_A<<<dim3(192), 256, 0, stream>>>(U, Ux, W, Wx, Ab);
    k_build_sbB<<<dim3(T_STEPS * 4), 256, 0, stream>>>(sb, sbB);

    const size_t hP = (size_t)2 * 64 * KH;   // 131072 elems per ping buffer
    for (int t = 0; t < T_STEPS; ++t) {
        k_step<<<dim3(256), 768, 0, stream>>>(
            Ab,
            sbB + (size_t)t * 2 * 64 * KX,
            hB + (size_t)(t & 1) * hP,
            hB + (size_t)((t + 1) & 1) * hP,
            out + (size_t)t * BATCH * DDIM,
            t ? out + (size_t)(t - 1) * BATCH * DDIM : out,
            bW, bWx,
            mask + (size_t)t * BATCH,
            t == 0 ? 1 : 0);
    }
}

// Round 11
// 5259.551 us; speedup vs baseline: 3.9323x; 1.0242x over previous
//
#include <hip/hip_runtime.h>
#include <math.h>

#define T_STEPS 512
#define BATCH   64
#define IDIM    512
#define DDIM    1024
#define KH      1024
#define KX      512
#define KT      1536
#define NBLK    256

typedef unsigned short ushort_t;
typedef unsigned long long ull_t;
typedef __attribute__((ext_vector_type(8))) short short8;
typedef __attribute__((ext_vector_type(4))) short short4v;
typedef __attribute__((ext_vector_type(4))) float f32x4;

union U16B { ull_t u[2]; short8 s; };

__device__ __forceinline__ ushort_t f2bf(float f) {
    unsigned int u = __float_as_uint(f);
    u += 0x7fff + ((u >> 16) & 1);          // RNE
    return (ushort_t)(u >> 16);
}
__device__ __forceinline__ float bf2f(ushort_t s) {
    return __uint_as_float(((unsigned int)s) << 16);
}

// ---------------------------------------------------------------------------
// One-time: weights -> Ab[dc 0..63][g 0..2][s 0..1][m 0..15][k 0..1535] bf16
// (proven; s=1 residual written but unread by the dual-product scan)
// ---------------------------------------------------------------------------
__global__ __launch_bounds__(256) void k_build_A(const float* __restrict__ U,
                                                 const float* __restrict__ Ux,
                                                 const float* __restrict__ W,
                                                 const float* __restrict__ Wx,
                                                 ushort_t* __restrict__ Ab) {
    int blk = blockIdx.x;            // 0..191 = dc*3+g
    int dc = blk / 3, g = blk % 3;
    int tid = threadIdx.x;
    int m = tid & 15, kb = tid >> 4;
    int col = dc * 16 + m;
    size_t rowbase = ((((size_t)dc * 3 + g) * 2 + 0) * 16 + m) * KT;
    for (int k = kb; k < KT; k += 16) {
        float w;
        if (g == 2) {
            w = (k < KH) ? Ux[(size_t)k * DDIM + col]
                         : Wx[(size_t)(k - KH) * DDIM + col];
        } else {
            int c2 = col + (g == 1 ? DDIM : 0);
            w = (k < KH) ? U[(size_t)k * (2 * DDIM) + c2]
                         : W[(size_t)(k - KH) * (2 * DDIM) + c2];
        }
        ushort_t w1 = f2bf(w);
        ushort_t w2 = f2bf(w - bf2f(w1));
        Ab[rowbase + k] = w1;
        Ab[rowbase + (size_t)16 * KT + k] = w2;   // s=1 (unused)
    }
}

// ---------------------------------------------------------------------------
// One-time: state_below -> sbB[t][s][b 0..63][i 0..511] bf16 (split pair)
// ---------------------------------------------------------------------------
__global__ __launch_bounds__(256) void k_build_sbB(const float* __restrict__ sb,
                                                   ushort_t* __restrict__ sbB) {
    int blk = blockIdx.x;            // 0..2047 = t*4+bt
    int t = blk >> 2, bt = blk & 3;
    int tid = threadIdx.x;
    int r = tid >> 4, c = tid & 15;
    const float* src = sb + ((size_t)t * BATCH + bt * 16 + r) * IDIM;
    ushort_t* d1 = sbB + ((((size_t)t * 2 + 0) * 4 + bt) * 16 + r) * KX;
    ushort_t* d2 = sbB + ((((size_t)t * 2 + 1) * 4 + bt) * 16 + r) * KX;
#pragma unroll
    for (int rep = 0; rep < 8; ++rep) {
        int i = c * 4 + rep * 64;
        float4 v = *(const float4*)(src + i);
        ushort_t a0 = f2bf(v.x), a1 = f2bf(v.y), a2 = f2bf(v.z), a3 = f2bf(v.w);
        short4v p1 = {(short)a0, (short)a1, (short)a2, (short)a3};
        *(short4v*)(d1 + i) = p1;
        ushort_t b0 = f2bf(v.x - bf2f(a0)), b1 = f2bf(v.y - bf2f(a1));
        ushort_t b2 = f2bf(v.z - bf2f(a2)), b3 = f2bf(v.w - bf2f(a3));
        short4v p2 = {(short)b0, (short)b1, (short)b2, (short)b3};
        *(short4v*)(d2 + i) = p2;
    }
}

// ---------------------------------------------------------------------------
// Two-level grid barrier, ALL-RELAXED polling (no acquire => no buffer_inv
// storm). cnt[xcd] at bar[xcd*32] (128-B lines), root bar[256], gen bar[288].
// Safe because h is exchanged via relaxed agent-scope atomics (coherent at
// L3 once vmcnt-retired; __syncthreads drains vmcnt before arrival).
// ---------------------------------------------------------------------------
__device__ __forceinline__ void gbar(int* __restrict__ bar, int xcd, int target) {
    int a = __hip_atomic_fetch_add(&bar[xcd * 32], 1, __ATOMIC_RELAXED,
                                   __HIP_MEMORY_SCOPE_AGENT);
    if (a == (NBLK / 8) - 1) {
        __hip_atomic_store(&bar[xcd * 32], 0, __ATOMIC_RELAXED,
                           __HIP_MEMORY_SCOPE_AGENT);
        int r = __hip_atomic_fetch_add(&bar[256], 1, __ATOMIC_RELAXED,
                                       __HIP_MEMORY_SCOPE_AGENT);
        if (r == 7) {
            __hip_atomic_store(&bar[256], 0, __ATOMIC_RELAXED,
                               __HIP_MEMORY_SCOPE_AGENT);
            __hip_atomic_store(&bar[288], target, __ATOMIC_RELAXED,
                               __HIP_MEMORY_SCOPE_AGENT);
        }
    }
    while (__hip_atomic_load(&bar[288], __ATOMIC_RELAXED,
                             __HIP_MEMORY_SCOPE_AGENT) < target)
        __builtin_amdgcn_s_sleep(1);
}

// ---------------------------------------------------------------------------
// Persistent scan. Grid 256 = (dc 0..63) x (bq 0..3) XCD-swizzled; 768 thr =
// 12 waves, wave ku = K-slice of 128 (ku<8: h via relaxed 8-B agent atomics,
// ku>=8: x via normal cached loads). A1 frags register-resident all 512 steps
// (dual-product: acc += A1*B2 + A1*B1). Per step: MFMA -> red LDS ->
// epilogue (hold in regs, 64 thr x 4 d) -> sync -> relaxed barrier -> sync.
// ---------------------------------------------------------------------------
__global__ __launch_bounds__(768, 1) void k_scan(
    const ushort_t* __restrict__ Ab, const ushort_t* __restrict__ sbB,
    const float* __restrict__ mask, const float* __restrict__ bW,
    const float* __restrict__ bWx, ushort_t* __restrict__ hB,
    float* __restrict__ out, int* __restrict__ bar)
{
    __shared__ float red[12 * 3 * 4 * 64];   // 36,864 B

    int tid  = threadIdx.x;
    int lane = tid & 63;
    int ku   = tid >> 6;                 // 0..11 = K-slice
    int bid  = blockIdx.x;
    int xcd  = bid & 7, j = bid >> 3;    // j 0..31
    int dc   = xcd * 8 + (j & 7);        // 0..63
    int bq   = j >> 3;                   // 0..3

    int m = lane & 15, q = lane >> 4;
    int b_lane = bq * 16 + m;

    bool isH  = (ku < 8);
    int kbase = isH ? ku * 128 : KH + (ku - 8) * 128;

    // ---- A1 fragments: registers for the whole scan (3 g x 4 k-steps)
    short8 A1r[3][4];
#pragma unroll
    for (int g = 0; g < 3; ++g) {
        const ushort_t* a1p =
            Ab + ((((size_t)dc * 3 + g) * 2 + 0) * 16 + m) * KT + kbase;
#pragma unroll
        for (int ks = 0; ks < 4; ++ks)
            A1r[g][ks] = *(const short8*)(a1p + ks * 32 + q * 8);
    }

    // ---- epilogue persistent state (tid<64: one b, 4 d's)
    int eb = 0, edb = 0;
    float4 bWr = {0,0,0,0}, bWu = {0,0,0,0}, bXx = {0,0,0,0};
    float hold[4] = {0.f, 0.f, 0.f, 0.f};
    if (tid < 64) {
        int qq = tid >> 4, b16 = tid & 15;
        eb  = bq * 16 + b16;
        edb = dc * 16 + qq * 4;
        bWr = *(const float4*)(bW + edb);
        bWu = *(const float4*)(bW + DDIM + edb);
        bXx = *(const float4*)(bWx + edb);
    }

    const size_t hP = (size_t)2 * 64 * KH;   // elems per ping buffer

    for (int t = 0; t < T_STEPS; ++t) {
        const ushort_t* hBin  = hB + (size_t)(t & 1) * hP;
        ushort_t*       hBout = hB + (size_t)((t + 1) & 1) * hP;

        f32x4 accA[3] = {{0,0,0,0},{0,0,0,0},{0,0,0,0}};
        f32x4 accB[3] = {{0,0,0,0},{0,0,0,0},{0,0,0,0}};

        if (isH) {
            if (t > 0) {
                const ushort_t* brow = hBin + (size_t)b_lane * KH + kbase;
#pragma unroll
                for (int ks = 0; ks < 4; ++ks) {
                    int off = ks * 32 + q * 8;
                    U16B x1, x2;
                    x1.u[0] = __hip_atomic_load((ull_t*)(brow + off),
                                                __ATOMIC_RELAXED, __HIP_MEMORY_SCOPE_AGENT);
                    x1.u[1] = __hip_atomic_load((ull_t*)(brow + off) + 1,
                                                __ATOMIC_RELAXED, __HIP_MEMORY_SCOPE_AGENT);
                    x2.u[0] = __hip_atomic_load((ull_t*)(brow + (size_t)64 * KH + off),
                                                __ATOMIC_RELAXED, __HIP_MEMORY_SCOPE_AGENT);
                    x2.u[1] = __hip_atomic_load((ull_t*)(brow + (size_t)64 * KH + off) + 1,
                                                __ATOMIC_RELAXED, __HIP_MEMORY_SCOPE_AGENT);
                    short8 B1 = x1.s, B2 = x2.s;
#pragma unroll
                    for (int g = 0; g < 3; ++g) {
                        f32x4* acc = (ks & 1) ? &accB[g] : &accA[g];
                        *acc = __builtin_amdgcn_mfma_f32_16x16x32_bf16(A1r[g][ks], B2, *acc, 0, 0, 0);
                        *acc = __builtin_amdgcn_mfma_f32_16x16x32_bf16(A1r[g][ks], B1, *acc, 0, 0, 0);
                    }
                }
            }
        } else {
            const ushort_t* brow =
                sbB + (size_t)t * (2 * 64 * KX) + (size_t)b_lane * KX + (kbase - KH);
#pragma unroll
            for (int ks = 0; ks < 4; ++ks) {
                int off = ks * 32 + q * 8;
                short8 B1 = *(const short8*)(brow + off);
                short8 B2 = *(const short8*)(brow + (size_t)64 * KX + off);
#pragma unroll
                for (int g = 0; g < 3; ++g) {
                    f32x4* acc = (ks & 1) ? &accB[g] : &accA[g];
                    *acc = __builtin_amdgcn_mfma_f32_16x16x32_bf16(A1r[g][ks], B2, *acc, 0, 0, 0);
                    *acc = __builtin_amdgcn_mfma_f32_16x16x32_bf16(A1r[g][ks], B1, *acc, 0, 0, 0);
                }
            }
        }

#pragma unroll
        for (int g = 0; g < 3; ++g) {
            f32x4 s = accA[g] + accB[g];
#pragma unroll
            for (int rg = 0; rg < 4; ++rg)
                red[((ku * 3 + g) * 4 + rg) * 64 + lane] = s[rg];
        }
        __syncthreads();

        // ---- epilogue: 64 threads, one b x 4 d each; hold in registers
        if (tid < 64) {
            int qq = tid >> 4, b16 = tid & 15;
            int l_src = (qq << 4) + b16;
            float mk = mask[(t << 6) + eb];
            float res[4];
            ushort_t h1[4], h2[4];
#pragma unroll
            for (int rg = 0; rg < 4; ++rg) {
                float sR = 0.f, sU = 0.f, sHu = 0.f, sXx = 0.f;
#pragma unroll
                for (int k2 = 0; k2 < 12; ++k2) {
                    sR += red[((k2 * 3 + 0) * 4 + rg) * 64 + l_src];
                    sU += red[((k2 * 3 + 1) * 4 + rg) * 64 + l_src];
                    float v2 = red[((k2 * 3 + 2) * 4 + rg) * 64 + l_src];
                    if (k2 < 8) sHu += v2; else sXx += v2;
                }
                float bRv = (rg == 0) ? bWr.x : (rg == 1) ? bWr.y : (rg == 2) ? bWr.z : bWr.w;
                float bUv = (rg == 0) ? bWu.x : (rg == 1) ? bWu.y : (rg == 2) ? bWu.z : bWu.w;
                float bXv = (rg == 0) ? bXx.x : (rg == 1) ? bXx.y : (rg == 2) ? bXx.z : bXx.w;
                float r  = 1.f / (1.f + __expf(-(sR + bRv)));
                float u  = 1.f / (1.f + __expf(-(sU + bUv)));
                float hc = tanhf(sHu * r + sXx + bXv);
                float hnv = u * hold[rg] + (1.f - u) * hc;
                hnv = mk * hnv + (1.f - mk) * hold[rg];
                hold[rg] = hnv;
                res[rg] = hnv;
                h1[rg] = f2bf(hnv);
                h2[rg] = f2bf(hnv - bf2f(h1[rg]));
            }
            float4 o = {res[0], res[1], res[2], res[3]};
            *(float4*)(out + (size_t)t * (BATCH * DDIM) + (size_t)eb * DDIM + edb) = o;
            ull_t v1 = (ull_t)h1[0] | ((ull_t)h1[1] << 16) | ((ull_t)h1[2] << 32) | ((ull_t)h1[3] << 48);
            ull_t v2 = (ull_t)h2[0] | ((ull_t)h2[1] << 16) | ((ull_t)h2[2] << 32) | ((ull_t)h2[3] << 48);
            __hip_atomic_store((ull_t*)(hBout + (size_t)eb * KH + edb), v1,
                               __ATOMIC_RELAXED, __HIP_MEMORY_SCOPE_AGENT);
            __hip_atomic_store((ull_t*)(hBout + (size_t)64 * KH + (size_t)eb * KH + edb), v2,
                               __ATOMIC_RELAXED, __HIP_MEMORY_SCOPE_AGENT);
        }

        __syncthreads();                       // drains epilogue vmcnt; red reusable
        if (t + 1 < T_STEPS) {
            if (tid == 0) gbar(bar, xcd, t + 1);
            __syncthreads();
        }
    }
}

// ---------------------------------------------------------------------------
extern "C" void kernel_launch(void* const* d_in, const int* in_sizes, int n_in,
                              void* d_out, int out_size, void* d_ws, size_t ws_size,
                              hipStream_t stream) {
    const float* sb   = (const float*)d_in[0];
    const float* mask = (const float*)d_in[1];
    const float* W    = (const float*)d_in[2];
    const float* bW   = (const float*)d_in[3];
    const float* Wx   = (const float*)d_in[4];
    const float* bWx  = (const float*)d_in[5];
    const float* U    = (const float*)d_in[6];
    const float* Ux   = (const float*)d_in[7];
    float* out = (float*)d_out;

    // ws layout (bf16 elems): Ab 9,437,184 | sbB 33,554,432 | hB 2x131,072 | bar
    ushort_t* Ab  = (ushort_t*)d_ws;
    ushort_t* sbB = Ab + (size_t)2 * 3072 * KT;
    ushort_t* hB  = sbB + (size_t)T_STEPS * 2 * 64 * KX;
    int*      bar = (int*)(hB + (size_t)2 * 2 * 64 * KH);

    (void)hipMemsetAsync(bar, 0, 2048, stream);
    k_build_A<<<dim3(192), 256, 0, stream>>>(U, Ux, W, Wx, Ab);
    k_build_sbB<<<dim3(T_STEPS * 4), 256, 0, stream>>>(sb, sbB);

    const ushort_t* AbC = Ab; const ushort_t* sbBC = sbB;
    void* args[] = {(void*)&AbC, (void*)&sbBC, (void*)&mask, (void*)&bW,
                    (void*)&bWx, (void*)&hB, (void*)&out, (void*)&bar};
    (void)hipLaunchCooperativeKernel((const void*)k_scan, dim3(NBLK), dim3(768),
                                     args, 0, stream);
}